// Round 5
// baseline (334.946 us; speedup 1.0000x reference)
//
#include <hip/hip_runtime.h>
#include <math.h>

typedef unsigned short u16;
typedef __attribute__((ext_vector_type(8))) short short8;   // 8 bf16 = 4 VGPRs
typedef __attribute__((ext_vector_type(4))) float floatx4;  // MFMA 16x16 C/D

// fp32 -> bf16 round-to-nearest-even
__device__ __forceinline__ u16 f2bf(float f) {
  union { float f; unsigned u; } v; v.f = f;
  unsigned r = (v.u + 0x7FFFu + ((v.u >> 16) & 1u)) >> 16;
  return (u16)r;
}

// async global->LDS, 16B per lane; LDS dest must be wave-uniform base + lane*16
#define GLD16(gp, lp) __builtin_amdgcn_global_load_lds(                      \
    (__attribute__((address_space(1))) void*)(gp),                           \
    (__attribute__((address_space(3))) void*)(lp), 16, 0, 0)

// ---------------------------------------------------------------------------
// f32 -> bf16 conversion: 5 tensors of 4194304 elements each, contiguous dst.
// ---------------------------------------------------------------------------
__global__ __launch_bounds__(256) void cvt_all(
    const float* __restrict__ H, const float* __restrict__ Wq,
    const float* __restrict__ Wk, const float* __restrict__ Wv,
    const float* __restrict__ Wo, u16* __restrict__ dst) {
  const float* srcs[5] = {H, Wq, Wk, Wv, Wo};
  const int sel = blockIdx.y;
  const float* s = srcs[sel];
  u16* d = dst + (size_t)sel * 4194304;
  const int idx = (blockIdx.x * 256 + threadIdx.x) * 4;
  const float4 v = *(const float4*)(s + idx);
  ushort4 o;
  o.x = f2bf(v.x); o.y = f2bf(v.y); o.z = f2bf(v.z); o.w = f2bf(v.w);
  *(ushort4*)(d + idx) = o;
}

// ---------------------------------------------------------------------------
// GEMM core: C[m,n] = sum_k A[m,k] * B[n,k]  (B^T layout, all dims 2048)
// 128x128 tile, BK=64, 4 waves each computing 64x64 (4x4 MFMA tiles).
// LDS column-chunk XOR swizzle vs 16-way bank conflicts (see R5 notes).
// mode 0: C row-major fp32 [2048,2048]  (final output)
// mode 1: head-split bf16   [bh,1024,64]   (Q,K; cscale folds 1/sqrt(D) into Q)
// mode 2: head-split-T bf16 [bh,64,1024]   (V^T)
// ---------------------------------------------------------------------------
__device__ __forceinline__ void gemm_core(const u16* __restrict__ A,
                                          const u16* __restrict__ B,
                                          u16* __restrict__ Cb,
                                          float* __restrict__ Cf,
                                          int M0, int N0, int mode, float cscale,
                                          u16* lA, u16* lB) {
  const int tid = threadIdx.x;
  const int lane = tid & 63;
  const int wave = tid >> 6;
  const int lq = lane & 15, quad = lane >> 4;
  const int wm = wave & 1, wn = wave >> 1;

  floatx4 acc[4][4];
#pragma unroll
  for (int i = 0; i < 4; ++i)
#pragma unroll
    for (int j = 0; j < 4; ++j) acc[i][j] = (floatx4)0.f;

  const int srow = tid >> 3;        // 0..31
  const int cc = tid & 7;           // column chunk 0..7

  for (int k0 = 0; k0 < 2048; k0 += 64) {
    __syncthreads();
#pragma unroll
    for (int r = 0; r < 4; ++r) {
      const int row = r * 32 + srow;
      const int gcol = ((cc ^ (row & 7)) << 3);   // swizzled global chunk
      const int flat = row * 64 + (cc << 3);      // contiguous LDS dest
      GLD16(A + (size_t)(M0 + row) * 2048 + k0 + gcol, lA + flat);
      GLD16(B + (size_t)(N0 + row) * 2048 + k0 + gcol, lB + flat);
    }
    __syncthreads();
    const int sw = lq & 7;
#pragma unroll
    for (int ks8 = 0; ks8 < 8; ks8 += 4) {        // ks = ks8*8 in {0,32}
      short8 af[4], bf[4];
#pragma unroll
      for (int t = 0; t < 4; ++t)
        af[t] = *(const short8*)&lA[(wm * 64 + t * 16 + lq) * 64 + (((quad + ks8) ^ sw) << 3)];
#pragma unroll
      for (int t = 0; t < 4; ++t)
        bf[t] = *(const short8*)&lB[(wn * 64 + t * 16 + lq) * 64 + (((quad + ks8) ^ sw) << 3)];
#pragma unroll
      for (int i = 0; i < 4; ++i)
#pragma unroll
        for (int j = 0; j < 4; ++j)
          acc[i][j] = __builtin_amdgcn_mfma_f32_16x16x32_bf16(af[i], bf[j], acc[i][j], 0, 0, 0);
    }
  }

  // epilogue: C/D layout col=lane&15, row=quad*4+reg
#pragma unroll
  for (int i = 0; i < 4; ++i)
#pragma unroll
    for (int j = 0; j < 4; ++j)
#pragma unroll
      for (int r = 0; r < 4; ++r) {
        const int m = M0 + wm * 64 + i * 16 + quad * 4 + r;
        const int n = N0 + wn * 64 + j * 16 + lq;
        if (mode == 0) {
          Cf[(size_t)m * 2048 + n] = acc[i][j][r];
        } else {
          const int bh = ((m >> 10) << 5) | (n >> 6);  // b*32 + head
          size_t addr;
          if (mode == 1) addr = ((size_t)bh * 1024 + (m & 1023)) * 64 + (n & 63);
          else           addr = ((size_t)bh * 64 + (n & 63)) * 1024 + (m & 1023);
          Cb[addr] = f2bf(acc[i][j][r] * cscale);
        }
      }
}

__global__ __launch_bounds__(256, 3) void gemm_qkv(
    const u16* __restrict__ H,
    const u16* __restrict__ Wq, const u16* __restrict__ Wk, const u16* __restrict__ Wv,
    u16* __restrict__ q, u16* __restrict__ k, u16* __restrict__ vt) {
  __shared__ __align__(16) u16 lA[128 * 64];
  __shared__ __align__(16) u16 lB[128 * 64];
  const int M0 = blockIdx.x * 128;
  const int sel = blockIdx.y >> 4;        // 0:Q 1:K 2:V
  const int N0 = (blockIdx.y & 15) * 128;
  const u16* B = (sel == 0) ? Wq : (sel == 1) ? Wk : Wv;
  u16* C = (sel == 0) ? q : (sel == 1) ? k : vt;
  gemm_core(H, B, C, nullptr, M0, N0, (sel == 2) ? 2 : 1,
            (sel == 0) ? 0.125f : 1.f, lA, lB);
}

__global__ __launch_bounds__(256, 3) void gemm_out(
    const u16* __restrict__ A, const u16* __restrict__ W, float* __restrict__ C) {
  __shared__ __align__(16) u16 lA[128 * 64];
  __shared__ __align__(16) u16 lB[128 * 64];
  gemm_core(A, W, nullptr, C, blockIdx.x * 128, blockIdx.y * 128, 0, 1.f, lA, lB);
}

// ---------------------------------------------------------------------------
// Stick-breaking attention, multiplicative form, transposed z:
//   p = sigmoid(z), att[i,j] = p(i,j) * prod_{j<k<i} (1 - p(i,k))
// z' = K·Q^T via MFMA -> C-layout: lane holds query=lq, keys=16c+quad*4+r.
// P written [query][key] (B-frag layout), PV = MFMA(A=Vt, B=P') -> O^T,
// transposed back through LDS for coalesced stores.
//
// R7/R9: key-range SPLIT across two waves per q-strip (upper incl. diagonal /
// lower): O = O_up + carry_up ⊙ O_lo. Grid 2048, (256,4) — the only measured
// spill-free point with 4 blocks/CU (cap ~512/waves_per_EU shared VGPR+AGPR:
// (256,3)->84ok, (256,4)->52-60ok, (256,6)->40+spill, (256,8)->32+spill).
//
// R10: occupancy exhausted as a lever (R5 30%occ == R9 37.5%occ == ~70us;
// VALUBusy pinned at 21% = 3 waves/SIMD x 7% per-wave duty). Cut the per-tile
// critical path (~5k cyc) instead:
//  * LDS-based suffix scan: lane writes its 4 quad-chunk products (1 float4),
//    one lgkm wait, reads the 16-product row back (4 float4, same-query lanes
//    broadcast, 2-way bank alias via SSTR=20 pad). All suffix products become
//    ~25 local VALU ops (depth ~6). Replaces 16 chained ~40cy cross-lane
//    shuffles AND the serial cross-chunk `cur` multiply chain.
//  * K-prefetch pipelining (R6-proven): next tile's 8 K loads issue before
//    the current body; mfma_z runs after, when they've landed. K-load latency
//    (~400-600cy L2/L3) hides under the ~1.5k-cy body.
// ---------------------------------------------------------------------------
#define PSTR 72   // P slab row stride in u16 (64 + 8 pad; rows 144B, 16B-aligned)
#define OSTR 20   // O_lo exchange stride in floats per lane (16 + 4 pad)
#define SSTR 20   // scan row stride in floats (16 + 4 pad; 80B, 16B-aligned)

__device__ __forceinline__ void load_k(
    int j0, int lq, int quad, const u16* __restrict__ kb0,
    short8 (&kf0)[4], short8 (&kf1)[4]) {
#pragma unroll
  for (int c = 0; c < 4; ++c) {
    const u16* kr = &kb0[(size_t)(j0 + 16 * c + lq) * 64 + quad * 8];
    kf0[c] = *(const short8*)kr;
    kf1[c] = *(const short8*)(kr + 32);
  }
}

__device__ __forceinline__ void mfma_z(
    const short8 (&kf0)[4], const short8 (&kf1)[4],
    const short8& qf0, const short8& qf1, floatx4 (&zc)[4]) {
#pragma unroll
  for (int c = 0; c < 4; ++c) {
    floatx4 z = (floatx4)0.f;
    z = __builtin_amdgcn_mfma_f32_16x16x32_bf16(kf0[c], qf0, z, 0, 0, 0);
    z = __builtin_amdgcn_mfma_f32_16x16x32_bf16(kf1[c], qf1, z, 0, 0, 0);
    zc[c] = z;
  }
}

template <bool MASKED>
__device__ __forceinline__ void sba_body(
    int j0, int q0, int lq, int quad,
    const u16* __restrict__ vb, u16* pw, float* scw,
    const floatx4 (&zc)[4],
    floatx4 (&o)[4], float& carry) {
  // V A-frags, first half (issued early; consumed ~1k cycles later)
  short8 vfA[4];
#pragma unroll
  for (int tt = 0; tt < 4; ++tt)
    vfA[tt] = *(const short8*)&vb[(size_t)(tt * 16 + lq) * 1024 + j0 + quad * 8];

  // sigmoid + within-quad-chunk exclusive suffixes: fully lane-local, all
  // 16 (c,r) pairs independent
  float p[4][4], e0[4], e1[4], e2[4], qt[4];
#pragma unroll
  for (int c = 0; c < 4; ++c) {
    float g[4];
#pragma unroll
    for (int r = 0; r < 4; ++r) {
      const float z = zc[c][r];
      const float e = __expf(-z);
      float pp = __builtin_amdgcn_rcpf(1.f + e);   // sigmoid
      float gg = e * pp;                            // 1 - sigmoid
      if (MASKED) {
        const bool valid = (j0 + 16 * c + quad * 4 + r) < (q0 + lq);
        gg = valid ? gg : 1.f;
        pp = valid ? pp : 0.f;
      }
      p[c][r] = pp; g[r] = gg;
    }
    e2[c] = g[3];
    e1[c] = e2[c] * g[2];
    e0[c] = e1[c] * g[1];
    qt[c] = e0[c] * g[0];      // product of this quad-chunk's 4 keys
  }
  // V second half (deferred past the sigmoid section: cuts peak VGPR)
  short8 vfB[4];
#pragma unroll
  for (int tt = 0; tt < 4; ++tt)
    vfB[tt] = *(const short8*)&vb[(size_t)(tt * 16 + lq) * 1024 + j0 + 32 + quad * 8];

  // LDS scan: publish 4 chunk-products; row lq = 16 products (quad-major)
  float4 w4; w4.x = qt[0]; w4.y = qt[1]; w4.z = qt[2]; w4.w = qt[3];
  *(float4*)&scw[lq * SSTR + quad * 4] = w4;
  __asm__ volatile("s_waitcnt lgkmcnt(0)" ::: "memory");  // own-wave visibility
  const float4 r0 = *(const float4*)&scw[lq * SSTR + 0];
  const float4 r1 = *(const float4*)&scw[lq * SSTR + 4];
  const float4 r2 = *(const float4*)&scw[lq * SSTR + 8];
  const float4 r3 = *(const float4*)&scw[lq * SSTR + 12];

  // C[c] = prod over all quads of chunk c; W[c] = prod over quads > mine
  float C[4], W[4];
#pragma unroll
  for (int c = 0; c < 4; ++c) {
    const float v0 = (&r0.x)[c], v1 = (&r1.x)[c];
    const float v2 = (&r2.x)[c], v3 = (&r3.x)[c];
    C[c] = (v0 * v1) * (v2 * v3);
    const float w1 = (quad < 1) ? v1 : 1.f;
    const float w2 = (quad < 2) ? v2 : 1.f;
    const float w3 = (quad < 3) ? v3 : 1.f;
    W[c] = w1 * (w2 * w3);
  }
  // bb[c] = carry * prod_{c'>c} C[c'];  key order: higher c = closer to diag
  float bb[4];
  bb[3] = carry;
  bb[2] = C[3] * carry;
  bb[1] = C[2] * bb[2];
  bb[0] = C[1] * bb[1];
  carry = C[0] * bb[0];

#pragma unroll
  for (int c = 0; c < 4; ++c) {
    const float QF = W[c] * bb[c];
    ushort4 pk;
    pk.x = f2bf(p[c][0] * (e0[c] * QF));
    pk.y = f2bf(p[c][1] * (e1[c] * QF));
    pk.z = f2bf(p[c][2] * (e2[c] * QF));
    pk.w = f2bf(p[c][3] * QF);
    *(ushort4*)&pw[lq * PSTR + c * 16 + quad * 4] = pk;  // [query][key] row-major
  }
  __asm__ volatile("s_waitcnt lgkmcnt(0)" ::: "memory");  // P visible to own wave
  const short8 pA = *(const short8*)&pw[lq * PSTR + quad * 8];       // keys j0+0..31
  const short8 pB = *(const short8*)&pw[lq * PSTR + 32 + quad * 8];  // keys j0+32..63
#pragma unroll
  for (int tt = 0; tt < 4; ++tt) {
    o[tt] = __builtin_amdgcn_mfma_f32_16x16x32_bf16(vfA[tt], pA, o[tt], 0, 0, 0);
    o[tt] = __builtin_amdgcn_mfma_f32_16x16x32_bf16(vfB[tt], pB, o[tt], 0, 0, 0);
  }
  // DS is in-order per wave: next tile's ds_write cannot pass the reads above.
}

// pipelined strip: K loads for tile t+1 issue before body(t)
template <bool MASK_FIRST>
__device__ __forceinline__ void run_strip(
    int jstart, int jend, int q0, int lq, int quad,
    const u16* __restrict__ kb0, const u16* __restrict__ vb,
    u16* pw, float* scw,
    const short8& qf0, const short8& qf1,
    floatx4 (&o)[4], float& carry) {
  short8 kf0[4], kf1[4];
  floatx4 zc[4];
  load_k(jstart, lq, quad, kb0, kf0, kf1);
  mfma_z(kf0, kf1, qf0, qf1, zc);
  int jn = jstart - 64;
  if (jn >= jend) load_k(jn, lq, quad, kb0, kf0, kf1);   // prefetch under body
  sba_body<MASK_FIRST>(jstart, q0, lq, quad, vb, pw, scw, zc, o, carry);
  while (jn >= jend) {
    mfma_z(kf0, kf1, qf0, qf1, zc);        // K[jn] landed during previous body
    const int j2 = jn - 64;
    if (j2 >= jend) load_k(j2, lq, quad, kb0, kf0, kf1);
    sba_body<false>(jn, q0, lq, quad, vb, pw, scw, zc, o, carry);
    jn = j2;
  }
}

__global__ __launch_bounds__(256, 4) void sba_attn(
    const u16* __restrict__ Q, const u16* __restrict__ Km,
    const u16* __restrict__ Vt, u16* __restrict__ AO) {
  __shared__ __align__(16) u16 lP[4][16 * PSTR];        //  9216 B
  __shared__ __align__(16) float oL[2][64 * OSTR];      // 10240 B (O_lo exchange)
  __shared__ __align__(16) float lS[4][16 * SSTR];      //  5120 B (scan rows)
  const int tid = threadIdx.x;
  const int lane = tid & 63;
  const int wave = tid >> 6;
  const int lq = lane & 15, quad = lane >> 4;
  // XCD-affinity swizzle: 32 consecutive blocks of one head land on one XCD
  const int blk = blockIdx.x;
  const int xcd = blk & 7, y = blk >> 3;         // y in [0,256)
  const int bh = xcd + 8 * (y >> 5);             // 8 heads per XCD slot
  const int w = y & 31;                          // strip-pair index
  const int strip = wave >> 1;                   // 0 / 1 within block
  const int role = wave & 1;                     // 0 = upper (incl diag), 1 = lower
  const int t = strip ? (63 - w) : w;            // pair (w, 63-w): balanced block
  const int q0 = t << 4;
  const int NT = (t >> 2) + 1;                   // 64-key tiles for this strip
  const int NU = (NT + 1) >> 1;                  // upper-wave tiles (>=1, has diag)
  const int NL = NT - NU;                        // lower-wave tiles (may be 0)

  // Q B-frags (pre-scaled by 1/8 in gemm_qkv): B[n=query=lq][k=d]
  const u16* qb = Q + ((size_t)bh * 1024 + q0) * 64;
  const short8 qf0 = *(const short8*)&qb[lq * 64 + quad * 8];
  const short8 qf1 = *(const short8*)&qb[lq * 64 + 32 + quad * 8];

  const u16* kb0 = Km + (size_t)bh * 65536;
  const u16* vb  = Vt + (size_t)bh * 65536;

  floatx4 o[4];
#pragma unroll
  for (int tt = 0; tt < 4; ++tt) o[tt] = (floatx4)0.f;
  float carry = 1.f;
  u16* pw = &lP[wave][0];
  float* scw = &lS[wave][0];

  if (role == 0) {
    // upper: diagonal tile (masked) then unmasked down to j0 == NL*64
    run_strip<true>(q0 & ~63, NL * 64, q0, lq, quad, kb0, vb, pw, scw,
                    qf0, qf1, o, carry);
  } else {
    // lower: keys [0, NL*64), all unmasked (strictly below q0)
    if (NL > 0)
      run_strip<false>((NL - 1) * 64, 0, q0, lq, quad, kb0, vb, pw, scw,
                       qf0, qf1, o, carry);
    // publish O_lo (zeros if NL==0)
#pragma unroll
    for (int tt = 0; tt < 4; ++tt)
      *(floatx4*)&oL[strip][lane * OSTR + tt * 4] = o[tt];
  }
  __syncthreads();
  if (role == 1) return;

  // combine: O = O_up + carry_up * O_lo (carry uniform across quads of a query:
  // all lanes compute identical C/bb values from the shared scan row)
#pragma unroll
  for (int tt = 0; tt < 4; ++tt) {
    const floatx4 ol = *(const floatx4*)&oL[strip][lane * OSTR + tt * 4];
#pragma unroll
    for (int r = 0; r < 4; ++r) o[tt][r] += carry * ol[r];
  }

  // O^T (d=tt*16+quad*4+r, query=lq) -> LDS [query][d] -> coalesced 16B stores
#pragma unroll
  for (int tt = 0; tt < 4; ++tt) {
    ushort4 pk;
    pk.x = f2bf(o[tt][0]); pk.y = f2bf(o[tt][1]);
    pk.z = f2bf(o[tt][2]); pk.w = f2bf(o[tt][3]);
    *(ushort4*)&pw[lq * PSTR + tt * 16 + quad * 4] = pk;
  }
  __asm__ volatile("s_waitcnt lgkmcnt(0)" ::: "memory");
  const int b = bh >> 5, hd = bh & 31;
#pragma unroll
  for (int ps = 0; ps < 2; ++ps) {
    const int row = lane >> 2;
    const int colu = ((lane & 3) + 4 * ps) * 8;
    const short8 val = *(const short8*)&pw[row * PSTR + colu];
    *(short8*)&AO[((size_t)b * 1024 + q0 + row) * 2048 + hd * 64 + colu] = val;
  }
}

extern "C" void kernel_launch(void* const* d_in, const int* in_sizes, int n_in,
                              void* d_out, int out_size, void* d_ws, size_t ws_size,
                              hipStream_t stream) {
  const float* H  = (const float*)d_in[0];
  const float* Wq = (const float*)d_in[1];
  const float* Wk = (const float*)d_in[2];
  const float* Wv = (const float*)d_in[3];
  const float* Wo = (const float*)d_in[4];

  u16* ws = (u16*)d_ws;
  u16* Hb  = ws;                  // [2048,2048] 8MB  (reused as ao after gemm_qkv)
  u16* Wqb = ws + 1 * 4194304;
  u16* Wkb = ws + 2 * 4194304;
  u16* Wvb = ws + 3 * 4194304;
  u16* Wob = ws + 4 * 4194304;
  u16* q   = ws + 5 * 4194304;    // [64,1024,64], pre-scaled by 1/8
  u16* k   = ws + 6 * 4194304;
  u16* vt  = ws + 7 * 4194304;    // [64,64,1024]
  u16* ao  = Hb;                  // alias: H consumed by gemm_qkv before sba_attn writes

  dim3 gc(4096, 5);
  cvt_all<<<gc, 256, 0, stream>>>(H, Wq, Wk, Wv, Wo, ws);

  dim3 gq(16, 48);
  gemm_qkv<<<gq, 256, 0, stream>>>(Hb, Wqb, Wkb, Wvb, q, k, vt);
  sba_attn<<<2048, 256, 0, stream>>>(q, k, vt, ao);
  dim3 go(16, 16);
  gemm_out<<<go, 256, 0, stream>>>(ao, Wob, (float*)d_out);
}

// Round 6
// 278.412 us; speedup vs baseline: 1.2031x; 1.2031x over previous
//
#include <hip/hip_runtime.h>
#include <math.h>

typedef unsigned short u16;
typedef __attribute__((ext_vector_type(8))) short short8;   // 8 bf16 = 4 VGPRs
typedef __attribute__((ext_vector_type(4))) float floatx4;  // MFMA 16x16 C/D

// fp32 -> bf16 round-to-nearest-even
__device__ __forceinline__ u16 f2bf(float f) {
  union { float f; unsigned u; } v; v.f = f;
  unsigned r = (v.u + 0x7FFFu + ((v.u >> 16) & 1u)) >> 16;
  return (u16)r;
}

// async global->LDS, 16B per lane; LDS dest must be wave-uniform base + lane*16
#define GLD16(gp, lp) __builtin_amdgcn_global_load_lds(                      \
    (__attribute__((address_space(1))) void*)(gp),                           \
    (__attribute__((address_space(3))) void*)(lp), 16, 0, 0)

// ---------------------------------------------------------------------------
// f32 -> bf16 conversion: 5 tensors of 4194304 elements each, contiguous dst.
// ---------------------------------------------------------------------------
__global__ __launch_bounds__(256) void cvt_all(
    const float* __restrict__ H, const float* __restrict__ Wq,
    const float* __restrict__ Wk, const float* __restrict__ Wv,
    const float* __restrict__ Wo, u16* __restrict__ dst) {
  const float* srcs[5] = {H, Wq, Wk, Wv, Wo};
  const int sel = blockIdx.y;
  const float* s = srcs[sel];
  u16* d = dst + (size_t)sel * 4194304;
  const int idx = (blockIdx.x * 256 + threadIdx.x) * 4;
  const float4 v = *(const float4*)(s + idx);
  ushort4 o;
  o.x = f2bf(v.x); o.y = f2bf(v.y); o.z = f2bf(v.z); o.w = f2bf(v.w);
  *(ushort4*)(d + idx) = o;
}

// ---------------------------------------------------------------------------
// GEMM core: C[m,n] = sum_{k in [kbeg,kend)} A[m,k] * B[n,k]  (B^T layout)
// 128x128 tile, BK=64, 4 waves each computing 64x64 (4x4 MFMA tiles).
// LDS column-chunk XOR swizzle vs 16-way bank conflicts (see R5 notes).
// mode 0: C row-major fp32 [2048,2048]  (final output / split-K partial)
// mode 1: head-split bf16   [bh,1024,64]   (Q,K; cscale folds 1/sqrt(D) into Q)
// mode 2: head-split-T bf16 [bh,64,1024]   (V^T)
// ---------------------------------------------------------------------------
__device__ __forceinline__ void gemm_core(const u16* __restrict__ A,
                                          const u16* __restrict__ B,
                                          u16* __restrict__ Cb,
                                          float* __restrict__ Cf,
                                          int M0, int N0, int mode, float cscale,
                                          u16* lA, u16* lB,
                                          int kbeg, int kend) {
  const int tid = threadIdx.x;
  const int lane = tid & 63;
  const int wave = tid >> 6;
  const int lq = lane & 15, quad = lane >> 4;
  const int wm = wave & 1, wn = wave >> 1;

  floatx4 acc[4][4];
#pragma unroll
  for (int i = 0; i < 4; ++i)
#pragma unroll
    for (int j = 0; j < 4; ++j) acc[i][j] = (floatx4)0.f;

  const int srow = tid >> 3;        // 0..31
  const int cc = tid & 7;           // column chunk 0..7

  for (int k0 = kbeg; k0 < kend; k0 += 64) {
    __syncthreads();
#pragma unroll
    for (int r = 0; r < 4; ++r) {
      const int row = r * 32 + srow;
      const int gcol = ((cc ^ (row & 7)) << 3);   // swizzled global chunk
      const int flat = row * 64 + (cc << 3);      // contiguous LDS dest
      GLD16(A + (size_t)(M0 + row) * 2048 + k0 + gcol, lA + flat);
      GLD16(B + (size_t)(N0 + row) * 2048 + k0 + gcol, lB + flat);
    }
    __syncthreads();
    const int sw = lq & 7;
#pragma unroll
    for (int ks8 = 0; ks8 < 8; ks8 += 4) {        // ks = ks8*8 in {0,32}
      short8 af[4], bf[4];
#pragma unroll
      for (int t = 0; t < 4; ++t)
        af[t] = *(const short8*)&lA[(wm * 64 + t * 16 + lq) * 64 + (((quad + ks8) ^ sw) << 3)];
#pragma unroll
      for (int t = 0; t < 4; ++t)
        bf[t] = *(const short8*)&lB[(wn * 64 + t * 16 + lq) * 64 + (((quad + ks8) ^ sw) << 3)];
#pragma unroll
      for (int i = 0; i < 4; ++i)
#pragma unroll
        for (int j = 0; j < 4; ++j)
          acc[i][j] = __builtin_amdgcn_mfma_f32_16x16x32_bf16(af[i], bf[j], acc[i][j], 0, 0, 0);
    }
  }

  // epilogue: C/D layout col=lane&15, row=quad*4+reg
#pragma unroll
  for (int i = 0; i < 4; ++i)
#pragma unroll
    for (int j = 0; j < 4; ++j)
#pragma unroll
      for (int r = 0; r < 4; ++r) {
        const int m = M0 + wm * 64 + i * 16 + quad * 4 + r;
        const int n = N0 + wn * 64 + j * 16 + lq;
        if (mode == 0) {
          Cf[(size_t)m * 2048 + n] = acc[i][j][r];
        } else {
          const int bh = ((m >> 10) << 5) | (n >> 6);  // b*32 + head
          size_t addr;
          if (mode == 1) addr = ((size_t)bh * 1024 + (m & 1023)) * 64 + (n & 63);
          else           addr = ((size_t)bh * 64 + (n & 63)) * 1024 + (m & 1023);
          Cb[addr] = f2bf(acc[i][j][r] * cscale);
        }
      }
}

__global__ __launch_bounds__(256, 3) void gemm_qkv(
    const u16* __restrict__ H,
    const u16* __restrict__ Wq, const u16* __restrict__ Wk, const u16* __restrict__ Wv,
    u16* __restrict__ q, u16* __restrict__ k, u16* __restrict__ vt) {
  __shared__ __align__(16) u16 lA[128 * 64];
  __shared__ __align__(16) u16 lB[128 * 64];
  const int M0 = blockIdx.x * 128;
  const int sel = blockIdx.y >> 4;        // 0:Q 1:K 2:V
  const int N0 = (blockIdx.y & 15) * 128;
  const u16* B = (sel == 0) ? Wq : (sel == 1) ? Wk : Wv;
  u16* C = (sel == 0) ? q : (sel == 1) ? k : vt;
  gemm_core(H, B, C, nullptr, M0, N0, (sel == 2) ? 2 : 1,
            (sel == 0) ? 0.125f : 1.f, lA, lB, 0, 2048);
}

// split-K=2: 512 blocks (2/CU vs 1/CU before) -> occupancy-starved fix.
// Partials go to dead workspace slots; reduce_add folds them into d_out.
__global__ __launch_bounds__(256, 3) void gemm_out(
    const u16* __restrict__ A, const u16* __restrict__ W,
    float* __restrict__ P0, float* __restrict__ P1) {
  __shared__ __align__(16) u16 lA[128 * 64];
  __shared__ __align__(16) u16 lB[128 * 64];
  float* Cf = blockIdx.z ? P1 : P0;
  const int kb = blockIdx.z * 1024;
  gemm_core(A, W, nullptr, Cf, blockIdx.x * 128, blockIdx.y * 128, 0, 1.f,
            lA, lB, kb, kb + 1024);
}

__global__ __launch_bounds__(256) void reduce_add(
    const float* __restrict__ P0, const float* __restrict__ P1,
    float* __restrict__ C) {
  const int i = (blockIdx.x * 256 + threadIdx.x) * 4;
  const float4 a = *(const float4*)(P0 + i);
  const float4 b = *(const float4*)(P1 + i);
  float4 o;
  o.x = a.x + b.x; o.y = a.y + b.y; o.z = a.z + b.z; o.w = a.w + b.w;
  *(float4*)(C + i) = o;
}

// ---------------------------------------------------------------------------
// Stick-breaking attention, multiplicative form, transposed z:
//   p = sigmoid(z), att[i,j] = p(i,j) * prod_{j<k<i} (1 - p(i,k))
// z' = K·Q^T via MFMA -> C-layout: lane holds query=lq, keys=16c+quad*4+r.
// P written [query][key] (B-frag layout), PV = MFMA(A=Vt, B=P') -> O^T,
// transposed back through LDS for coalesced stores.
//
// R7/R9: key-range SPLIT across two waves per q-strip (upper incl. diagonal /
// lower): O = O_up + carry_up ⊙ O_lo. Grid 2048, (256,4) — the only measured
// spill-free point with 4 blocks/CU (unified VGPR+AGPR cap ~128/wave there;
// R10 showed +64 live regs (K-prefetch + scan arrays) => 280MB spill traffic).
//
// R11: scan de-chaining ONLY, register-light (~+25 transient regs, no
// K-prefetch). Old scan: per chunk c, 3 CHAINED shuffles + a serial cross-c
// `cur` multiply chain = 16 dependent ~100cy DS ops on the critical path.
// New: 2-level butterfly with all 4 chunks in parallel:
//   s1[c]=shfl_xor(x[c],16); pp=x*s1; s2[c]=shfl_xor(pp,32);
//   T[c]=pp*s2 (total, quad-uniform); W[c]=within-pair-suffix * cross-pair;
//   bb[c]=carry*prod_{c'>c}T[c'] lane-local. Chain: 2 DS levels (~250cy).
// Carry/combine math identical to R10 (correctness-verified there).
// ---------------------------------------------------------------------------
#define PSTR 72   // P slab row stride in u16 (64 + 8 pad; rows 144B, 16B-aligned)
#define OSTR 20   // O_lo exchange stride in floats per lane (16 + 4 pad)

template <bool MASKED>
__device__ __forceinline__ void sba_tile(
    int j0, int q0, int lq, int quad,
    const u16* __restrict__ kb0, const u16* __restrict__ vb, u16* pw,
    const short8& qf0, const short8& qf1,
    floatx4 (&o)[4], float& carry) {
  // K A-frags: A[m=key 16c+lq][k=d chunk]
  short8 kf0[4], kf1[4];
#pragma unroll
  for (int c = 0; c < 4; ++c) {
    const u16* kr = &kb0[(size_t)(j0 + 16 * c + lq) * 64 + quad * 8];
    kf0[c] = *(const short8*)kr;
    kf1[c] = *(const short8*)(kr + 32);
  }
  floatx4 zc[4];
#pragma unroll
  for (int c = 0; c < 4; ++c) {
    floatx4 z = (floatx4)0.f;
    z = __builtin_amdgcn_mfma_f32_16x16x32_bf16(kf0[c], qf0, z, 0, 0, 0);
    z = __builtin_amdgcn_mfma_f32_16x16x32_bf16(kf1[c], qf1, z, 0, 0, 0);
    zc[c] = z;
  }
  // V A-frags, first half (issued early; consumed ~1k cycles later)
  short8 vfA[4];
#pragma unroll
  for (int tt = 0; tt < 4; ++tt)
    vfA[tt] = *(const short8*)&vb[(size_t)(tt * 16 + lq) * 1024 + j0 + quad * 8];

  // sigmoid + within-quad exclusive suffixes: all 16 (c,r) pairs independent
  float p[4][4], e0[4], e1[4], e2[4], x[4];
#pragma unroll
  for (int c = 0; c < 4; ++c) {
    float g[4];
#pragma unroll
    for (int r = 0; r < 4; ++r) {
      const float z = zc[c][r];
      const float e = __expf(-z);
      float pp = __builtin_amdgcn_rcpf(1.f + e);   // sigmoid
      float gg = e * pp;                            // 1 - sigmoid
      if (MASKED) {
        const bool valid = (j0 + 16 * c + quad * 4 + r) < (q0 + lq);
        gg = valid ? gg : 1.f;
        pp = valid ? pp : 0.f;
      }
      p[c][r] = pp; g[r] = gg;
    }
    e2[c] = g[3];
    e1[c] = e2[c] * g[2];
    e0[c] = e1[c] * g[1];
    x[c]  = e0[c] * g[0];      // product of this quad-chunk's 4 keys
  }

  // 2-level butterfly scan, all chunks in parallel (chain: 2 shuffle levels)
  float s1[4], pp[4], s2[4];
#pragma unroll
  for (int c = 0; c < 4; ++c) s1[c] = __shfl_xor(x[c], 16);
#pragma unroll
  for (int c = 0; c < 4; ++c) pp[c] = x[c] * s1[c];      // pair {q, q^1} product
#pragma unroll
  for (int c = 0; c < 4; ++c) s2[c] = __shfl_xor(pp[c], 32);  // other pair's product
  float T[4], W[4];
#pragma unroll
  for (int c = 0; c < 4; ++c) {
    T[c] = pp[c] * s2[c];                       // chunk total (quad-uniform)
    const float hi = (quad & 1) ? 1.f : s1[c];  // within-pair suffix (x of q+1)
    W[c] = hi * ((quad < 2) ? s2[c] : 1.f);     // prod over quads > mine
  }
  // bb[c] = carry * prod_{c'>c} T[c'] (higher c = closer to diagonal)
  float bb[4];
  bb[3] = carry;
  bb[2] = T[3] * bb[3];
  bb[1] = T[2] * bb[2];
  bb[0] = T[1] * bb[1];
  carry = T[0] * bb[0];

#pragma unroll
  for (int c = 0; c < 4; ++c) {
    const float QF = W[c] * bb[c];
    ushort4 pk;
    pk.x = f2bf(p[c][0] * (e0[c] * QF));
    pk.y = f2bf(p[c][1] * (e1[c] * QF));
    pk.z = f2bf(p[c][2] * (e2[c] * QF));
    pk.w = f2bf(p[c][3] * QF);
    *(ushort4*)&pw[lq * PSTR + c * 16 + quad * 4] = pk;  // [query][key] row-major
  }
  // V second half (deferred past the scan/pack: cuts peak VGPR)
  short8 vfB[4];
#pragma unroll
  for (int tt = 0; tt < 4; ++tt)
    vfB[tt] = *(const short8*)&vb[(size_t)(tt * 16 + lq) * 1024 + j0 + 32 + quad * 8];

  __asm__ volatile("s_waitcnt lgkmcnt(0)" ::: "memory");  // P visible to own wave
  const short8 pA = *(const short8*)&pw[lq * PSTR + quad * 8];       // keys j0+0..31
  const short8 pB = *(const short8*)&pw[lq * PSTR + 32 + quad * 8];  // keys j0+32..63
#pragma unroll
  for (int tt = 0; tt < 4; ++tt) {
    o[tt] = __builtin_amdgcn_mfma_f32_16x16x32_bf16(vfA[tt], pA, o[tt], 0, 0, 0);
    o[tt] = __builtin_amdgcn_mfma_f32_16x16x32_bf16(vfB[tt], pB, o[tt], 0, 0, 0);
  }
  // DS is in-order per wave: next tile's ds_write cannot pass the reads above.
}

__global__ __launch_bounds__(256, 4) void sba_attn(
    const u16* __restrict__ Q, const u16* __restrict__ Km,
    const u16* __restrict__ Vt, u16* __restrict__ AO) {
  __shared__ __align__(16) u16 lP[4][16 * PSTR];        //  9216 B
  __shared__ __align__(16) float oL[2][64 * OSTR];      // 10240 B (O_lo exchange)
  const int tid = threadIdx.x;
  const int lane = tid & 63;
  const int wave = tid >> 6;
  const int lq = lane & 15, quad = lane >> 4;
  // XCD-affinity swizzle: 32 consecutive blocks of one head land on one XCD
  const int blk = blockIdx.x;
  const int xcd = blk & 7, y = blk >> 3;         // y in [0,256)
  const int bh = xcd + 8 * (y >> 5);             // 8 heads per XCD slot
  const int w = y & 31;                          // strip-pair index
  const int strip = wave >> 1;                   // 0 / 1 within block
  const int role = wave & 1;                     // 0 = upper (incl diag), 1 = lower
  const int t = strip ? (63 - w) : w;            // pair (w, 63-w): balanced block
  const int q0 = t << 4;
  const int NT = (t >> 2) + 1;                   // 64-key tiles for this strip
  const int NU = (NT + 1) >> 1;                  // upper-wave tiles (>=1, has diag)
  const int NL = NT - NU;                        // lower-wave tiles (may be 0)

  // Q B-frags (pre-scaled by 1/8 in gemm_qkv): B[n=query=lq][k=d]
  const u16* qb = Q + ((size_t)bh * 1024 + q0) * 64;
  const short8 qf0 = *(const short8*)&qb[lq * 64 + quad * 8];
  const short8 qf1 = *(const short8*)&qb[lq * 64 + 32 + quad * 8];

  const u16* kb0 = Km + (size_t)bh * 65536;
  const u16* vb  = Vt + (size_t)bh * 65536;

  floatx4 o[4];
#pragma unroll
  for (int tt = 0; tt < 4; ++tt) o[tt] = (floatx4)0.f;
  float carry = 1.f;
  u16* pw = &lP[wave][0];

  if (role == 0) {
    // upper: diagonal tile (masked) then unmasked down to j0 == NL*64
    const int j0d = q0 & ~63;                    // == (NT-1)*64
    sba_tile<true>(j0d, q0, lq, quad, kb0, vb, pw, qf0, qf1, o, carry);
    for (int j0 = j0d - 64; j0 >= NL * 64; j0 -= 64)
      sba_tile<false>(j0, q0, lq, quad, kb0, vb, pw, qf0, qf1, o, carry);
  } else {
    // lower: keys [0, NL*64), all unmasked (strictly below q0)
    for (int j0 = (NL - 1) * 64; j0 >= 0; j0 -= 64)
      sba_tile<false>(j0, q0, lq, quad, kb0, vb, pw, qf0, qf1, o, carry);
    // publish O_lo (zeros if NL==0)
#pragma unroll
    for (int tt = 0; tt < 4; ++tt)
      *(floatx4*)&oL[strip][lane * OSTR + tt * 4] = o[tt];
  }
  __syncthreads();
  if (role == 1) return;

  // combine: O = O_up + carry_up * O_lo (carry is quad-uniform per query:
  // T[c] identical across quads by construction)
#pragma unroll
  for (int tt = 0; tt < 4; ++tt) {
    const floatx4 ol = *(const floatx4*)&oL[strip][lane * OSTR + tt * 4];
#pragma unroll
    for (int r = 0; r < 4; ++r) o[tt][r] += carry * ol[r];
  }

  // O^T (d=tt*16+quad*4+r, query=lq) -> LDS [query][d] -> coalesced 16B stores
#pragma unroll
  for (int tt = 0; tt < 4; ++tt) {
    ushort4 pk;
    pk.x = f2bf(o[tt][0]); pk.y = f2bf(o[tt][1]);
    pk.z = f2bf(o[tt][2]); pk.w = f2bf(o[tt][3]);
    *(ushort4*)&pw[lq * PSTR + tt * 16 + quad * 4] = pk;
  }
  __asm__ volatile("s_waitcnt lgkmcnt(0)" ::: "memory");
  const int b = bh >> 5, hd = bh & 31;
#pragma unroll
  for (int ps = 0; ps < 2; ++ps) {
    const int row = lane >> 2;
    const int colu = ((lane & 3) + 4 * ps) * 8;
    const short8 val = *(const short8*)&pw[row * PSTR + colu];
    *(short8*)&AO[((size_t)b * 1024 + q0 + row) * 2048 + hd * 64 + colu] = val;
  }
}

extern "C" void kernel_launch(void* const* d_in, const int* in_sizes, int n_in,
                              void* d_out, int out_size, void* d_ws, size_t ws_size,
                              hipStream_t stream) {
  const float* H  = (const float*)d_in[0];
  const float* Wq = (const float*)d_in[1];
  const float* Wk = (const float*)d_in[2];
  const float* Wv = (const float*)d_in[3];
  const float* Wo = (const float*)d_in[4];

  u16* ws = (u16*)d_ws;
  u16* Hb  = ws;                  // [2048,2048] 8MB  (reused as ao after gemm_qkv)
  u16* Wqb = ws + 1 * 4194304;
  u16* Wkb = ws + 2 * 4194304;
  u16* Wvb = ws + 3 * 4194304;
  u16* Wob = ws + 4 * 4194304;
  u16* q   = ws + 5 * 4194304;    // [64,1024,64], pre-scaled by 1/8
  u16* k   = ws + 6 * 4194304;
  u16* vt  = ws + 7 * 4194304;    // [64,64,1024]
  u16* ao  = Hb;                  // alias: H consumed by gemm_qkv before sba_attn writes
  // split-K partials (fp32, 16MB each) over DEAD slots:
  //   P0 over Wqb+Wkb (dead after gemm_qkv); P1 over q+k (dead after sba_attn)
  float* P0 = (float*)(ws + 1 * 4194304);
  float* P1 = (float*)(ws + 5 * 4194304);

  dim3 gc(4096, 5);
  cvt_all<<<gc, 256, 0, stream>>>(H, Wq, Wk, Wv, Wo, ws);

  dim3 gq(16, 48);
  gemm_qkv<<<gq, 256, 0, stream>>>(Hb, Wqb, Wkb, Wvb, q, k, vt);
  sba_attn<<<2048, 256, 0, stream>>>(q, k, vt, ao);
  dim3 go(16, 16, 2);
  gemm_out<<<go, 256, 0, stream>>>(ao, Wob, P0, P1);
  reduce_add<<<4096, 256, 0, stream>>>(P0, P1, (float*)d_out);
}

// Round 8
// 244.878 us; speedup vs baseline: 1.3678x; 1.1369x over previous
//
#include <hip/hip_runtime.h>
#include <math.h>

typedef unsigned short u16;
typedef __attribute__((ext_vector_type(8))) short short8;   // 8 bf16 = 4 VGPRs
typedef __attribute__((ext_vector_type(4))) float floatx4;  // MFMA 16x16 C/D

// fp32 -> bf16 round-to-nearest-even
__device__ __forceinline__ u16 f2bf(float f) {
  union { float f; unsigned u; } v; v.f = f;
  unsigned r = (v.u + 0x7FFFu + ((v.u >> 16) & 1u)) >> 16;
  return (u16)r;
}

// async global->LDS, 16B per lane; LDS dest must be wave-uniform base + lane*16
#define GLD16(gp, lp) __builtin_amdgcn_global_load_lds(                      \
    (__attribute__((address_space(1))) void*)(gp),                           \
    (__attribute__((address_space(3))) void*)(lp), 16, 0, 0)

// ---------------------------------------------------------------------------
// f32 -> bf16 conversion: 5 tensors of 4194304 elements each, contiguous dst.
// ---------------------------------------------------------------------------
__global__ __launch_bounds__(256) void cvt_all(
    const float* __restrict__ H, const float* __restrict__ Wq,
    const float* __restrict__ Wk, const float* __restrict__ Wv,
    const float* __restrict__ Wo, u16* __restrict__ dst) {
  const float* srcs[5] = {H, Wq, Wk, Wv, Wo};
  const int sel = blockIdx.y;
  const float* s = srcs[sel];
  u16* d = dst + (size_t)sel * 4194304;
  const int idx = (blockIdx.x * 256 + threadIdx.x) * 4;
  const float4 v = *(const float4*)(s + idx);
  ushort4 o;
  o.x = f2bf(v.x); o.y = f2bf(v.y); o.z = f2bf(v.z); o.w = f2bf(v.w);
  *(ushort4*)(d + idx) = o;
}

// ---------------------------------------------------------------------------
// GEMM core: C[m,n] = sum_{k in [kbeg,kend)} A[m,k] * B[n,k]  (B^T layout)
// 128x128 tile, BK=64, 4 waves each computing 64x64 (4x4 MFMA tiles).
// LDS column-chunk XOR swizzle vs 16-way bank conflicts (see R5 notes).
// mode 0: C row-major fp32 [2048,2048]  (final output / split-K partial)
// mode 1: head-split bf16   [bh,1024,64]   (Q,K; cscale folds 1/sqrt(D) into Q)
// mode 2: head-split-T bf16 [bh,64,1024]   (V^T)
// ---------------------------------------------------------------------------
__device__ __forceinline__ void gemm_core(const u16* __restrict__ A,
                                          const u16* __restrict__ B,
                                          u16* __restrict__ Cb,
                                          float* __restrict__ Cf,
                                          int M0, int N0, int mode, float cscale,
                                          u16* lA, u16* lB,
                                          int kbeg, int kend) {
  const int tid = threadIdx.x;
  const int lane = tid & 63;
  const int wave = tid >> 6;
  const int lq = lane & 15, quad = lane >> 4;
  const int wm = wave & 1, wn = wave >> 1;

  floatx4 acc[4][4];
#pragma unroll
  for (int i = 0; i < 4; ++i)
#pragma unroll
    for (int j = 0; j < 4; ++j) acc[i][j] = (floatx4)0.f;

  const int srow = tid >> 3;        // 0..31
  const int cc = tid & 7;           // column chunk 0..7

  for (int k0 = kbeg; k0 < kend; k0 += 64) {
    __syncthreads();
#pragma unroll
    for (int r = 0; r < 4; ++r) {
      const int row = r * 32 + srow;
      const int gcol = ((cc ^ (row & 7)) << 3);   // swizzled global chunk
      const int flat = row * 64 + (cc << 3);      // contiguous LDS dest
      GLD16(A + (size_t)(M0 + row) * 2048 + k0 + gcol, lA + flat);
      GLD16(B + (size_t)(N0 + row) * 2048 + k0 + gcol, lB + flat);
    }
    __syncthreads();
    const int sw = lq & 7;
#pragma unroll
    for (int ks8 = 0; ks8 < 8; ks8 += 4) {        // ks = ks8*8 in {0,32}
      short8 af[4], bf[4];
#pragma unroll
      for (int t = 0; t < 4; ++t)
        af[t] = *(const short8*)&lA[(wm * 64 + t * 16 + lq) * 64 + (((quad + ks8) ^ sw) << 3)];
#pragma unroll
      for (int t = 0; t < 4; ++t)
        bf[t] = *(const short8*)&lB[(wn * 64 + t * 16 + lq) * 64 + (((quad + ks8) ^ sw) << 3)];
#pragma unroll
      for (int i = 0; i < 4; ++i)
#pragma unroll
        for (int j = 0; j < 4; ++j)
          acc[i][j] = __builtin_amdgcn_mfma_f32_16x16x32_bf16(af[i], bf[j], acc[i][j], 0, 0, 0);
    }
  }

  // epilogue: C/D layout col=lane&15, row=quad*4+reg
#pragma unroll
  for (int i = 0; i < 4; ++i)
#pragma unroll
    for (int j = 0; j < 4; ++j)
#pragma unroll
      for (int r = 0; r < 4; ++r) {
        const int m = M0 + wm * 64 + i * 16 + quad * 4 + r;
        const int n = N0 + wn * 64 + j * 16 + lq;
        if (mode == 0) {
          Cf[(size_t)m * 2048 + n] = acc[i][j][r];
        } else {
          const int bh = ((m >> 10) << 5) | (n >> 6);  // b*32 + head
          size_t addr;
          if (mode == 1) addr = ((size_t)bh * 1024 + (m & 1023)) * 64 + (n & 63);
          else           addr = ((size_t)bh * 64 + (n & 63)) * 1024 + (m & 1023);
          Cb[addr] = f2bf(acc[i][j][r] * cscale);
        }
      }
}

__global__ __launch_bounds__(256, 3) void gemm_qkv(
    const u16* __restrict__ H,
    const u16* __restrict__ Wq, const u16* __restrict__ Wk, const u16* __restrict__ Wv,
    u16* __restrict__ q, u16* __restrict__ k, u16* __restrict__ vt) {
  __shared__ __align__(16) u16 lA[128 * 64];
  __shared__ __align__(16) u16 lB[128 * 64];
  const int M0 = blockIdx.x * 128;
  const int sel = blockIdx.y >> 4;        // 0:Q 1:K 2:V
  const int N0 = (blockIdx.y & 15) * 128;
  const u16* B = (sel == 0) ? Wq : (sel == 1) ? Wk : Wv;
  u16* C = (sel == 0) ? q : (sel == 1) ? k : vt;
  gemm_core(H, B, C, nullptr, M0, N0, (sel == 2) ? 2 : 1,
            (sel == 0) ? 0.125f : 1.f, lA, lB, 0, 2048);
}

// split-K=2: 512 blocks (2/CU vs 1/CU before) -> occupancy-starved fix.
// Partials go to dead workspace slots; reduce_add folds them into d_out.
__global__ __launch_bounds__(256, 3) void gemm_out(
    const u16* __restrict__ A, const u16* __restrict__ W,
    float* __restrict__ P0, float* __restrict__ P1) {
  __shared__ __align__(16) u16 lA[128 * 64];
  __shared__ __align__(16) u16 lB[128 * 64];
  float* Cf = blockIdx.z ? P1 : P0;
  const int kb = blockIdx.z * 1024;
  gemm_core(A, W, nullptr, Cf, blockIdx.x * 128, blockIdx.y * 128, 0, 1.f,
            lA, lB, kb, kb + 1024);
}

__global__ __launch_bounds__(256) void reduce_add(
    const float* __restrict__ P0, const float* __restrict__ P1,
    float* __restrict__ C) {
  const int i = (blockIdx.x * 256 + threadIdx.x) * 4;
  const float4 a = *(const float4*)(P0 + i);
  const float4 b = *(const float4*)(P1 + i);
  float4 o;
  o.x = a.x + b.x; o.y = a.y + b.y; o.z = a.z + b.z; o.w = a.w + b.w;
  *(float4*)(C + i) = o;
}

// ---------------------------------------------------------------------------
// Stick-breaking attention, multiplicative form, transposed z:
//   p = sigmoid(z), att[i,j] = p(i,j) * prod_{j<k<i} (1 - p(i,k))
// z' = K·Q^T via MFMA -> C-layout: lane holds query=lq, keys=16c+quad*4+r.
// P written [query][key] (B-frag layout), PV = MFMA(A=Vt, B=P') -> O^T,
// transposed back through LDS for coalesced stores.
//
// R12 restructure (R5..R11 all ~70us regardless of occupancy/ILP/scan form;
// the invariant was 16 scattered per-wave VMEM instrs/tile, each lane-split
// over 16 cache lines, latency exposed per instr, re-fetched per wave):
//   BLOCK-COOPERATIVE staging. One block = 64 consecutive queries (4 waves x
//   16); all waves sweep the SAME j0 from the diagonal tile down to 0, so the
//   K/V 64x64 tiles are block-shared: staged once per tile via GLD16
//   (4 coalesced 16B loads/thread), double-buffered, async under compute.
//   Wave balance is exact (same tile count per wave); the R7 carry/O-combine
//   machinery is gone (each wave owns its 16 queries end-to-end).
//   Masked predicate key<q handles the shared diagonal tile for every wave.
//   LDS layout = gemm_core's column-chunk XOR swizzle with pre-swizzled
//   global source (both-sides-or-neither). LPT dispatch: longest blocks
//   (b=15, 16 tiles) first; bh=blk&63 keeps each head on one XCD.
// Sigmoid/butterfly-scan/carry/P->PV: verbatim R11 (correctness-proven).
// LDS 41984B -> 3 blocks/CU (12 waves/CU, same residency as R9/R11).
// (R13 = R12 resubmitted verbatim: container infra failure, no measurement.)
// ---------------------------------------------------------------------------
#define PSTR 72   // P slab row stride in u16 (64 + 8 pad; rows 144B, 16B-aligned)

__device__ __forceinline__ void stage_kv(
    int tid, const u16* __restrict__ kb0, const u16* __restrict__ vb, int j0,
    u16* dK, u16* dV) {
#pragma unroll
  for (int it = 0; it < 2; ++it) {
    const int s = it * 256 + tid;           // slot 0..511
    const int row = s >> 3, cc = s & 7;     // 64 rows x 8 chunks of 16B
    const int gc = (cc ^ (row & 7)) << 3;   // pre-swizzled global chunk
    const int flat = row * 64 + (cc << 3);  // contiguous LDS dest (GLD16 law)
    GLD16(kb0 + (size_t)(j0 + row) * 64 + gc, dK + flat);
    GLD16(vb + (size_t)row * 1024 + j0 + gc, dV + flat);
  }
}

template <bool MASKED>
__device__ __forceinline__ void sba_tile_lds(
    int j0, int q0w, int lq, int quad,
    const u16* __restrict__ lK, const u16* __restrict__ lV, u16* pw,
    const short8& qf0, const short8& qf1,
    floatx4 (&o)[4], float& carry) {
  const int sw = lq & 7;
  // K A-frags from LDS (swizzled chunks): A[m=key 16c+lq][k=d chunk]
  short8 kf0[4], kf1[4];
#pragma unroll
  for (int c = 0; c < 4; ++c) {
    const u16* kr = &lK[(16 * c + lq) * 64];
    kf0[c] = *(const short8*)&kr[(quad ^ sw) << 3];
    kf1[c] = *(const short8*)&kr[((quad + 4) ^ sw) << 3];
  }
  floatx4 zc[4];
#pragma unroll
  for (int c = 0; c < 4; ++c) {
    floatx4 z = (floatx4)0.f;
    z = __builtin_amdgcn_mfma_f32_16x16x32_bf16(kf0[c], qf0, z, 0, 0, 0);
    z = __builtin_amdgcn_mfma_f32_16x16x32_bf16(kf1[c], qf1, z, 0, 0, 0);
    zc[c] = z;
  }
  // V A-frags from LDS: rows = d (tt*16+lq), key chunks quad / quad+4
  short8 vfA[4], vfB[4];
#pragma unroll
  for (int tt = 0; tt < 4; ++tt) {
    const u16* vr = &lV[(tt * 16 + lq) * 64];
    vfA[tt] = *(const short8*)&vr[(quad ^ sw) << 3];
    vfB[tt] = *(const short8*)&vr[((quad + 4) ^ sw) << 3];
  }

  // sigmoid + within-quad exclusive suffixes: all 16 (c,r) pairs independent
  float p[4][4], e0[4], e1[4], e2[4], x[4];
#pragma unroll
  for (int c = 0; c < 4; ++c) {
    float g[4];
#pragma unroll
    for (int r = 0; r < 4; ++r) {
      const float z = zc[c][r];
      const float e = __expf(-z);
      float pp = __builtin_amdgcn_rcpf(1.f + e);   // sigmoid
      float gg = e * pp;                            // 1 - sigmoid
      if (MASKED) {
        const bool valid = (j0 + 16 * c + quad * 4 + r) < (q0w + lq);
        gg = valid ? gg : 1.f;
        pp = valid ? pp : 0.f;
      }
      p[c][r] = pp; g[r] = gg;
    }
    e2[c] = g[3];
    e1[c] = e2[c] * g[2];
    e0[c] = e1[c] * g[1];
    x[c]  = e0[c] * g[0];      // product of this quad-chunk's 4 keys
  }

  // 2-level butterfly scan, all chunks in parallel (chain: 2 shuffle levels)
  float s1[4], pp[4], s2[4];
#pragma unroll
  for (int c = 0; c < 4; ++c) s1[c] = __shfl_xor(x[c], 16);
#pragma unroll
  for (int c = 0; c < 4; ++c) pp[c] = x[c] * s1[c];      // pair {q, q^1} product
#pragma unroll
  for (int c = 0; c < 4; ++c) s2[c] = __shfl_xor(pp[c], 32);  // other pair's product
  float T[4], W[4];
#pragma unroll
  for (int c = 0; c < 4; ++c) {
    T[c] = pp[c] * s2[c];                       // chunk total (quad-uniform)
    const float hi = (quad & 1) ? 1.f : s1[c];  // within-pair suffix (x of q+1)
    W[c] = hi * ((quad < 2) ? s2[c] : 1.f);     // prod over quads > mine
  }
  // bb[c] = carry * prod_{c'>c} T[c'] (higher c = closer to diagonal)
  float bb[4];
  bb[3] = carry;
  bb[2] = T[3] * bb[3];
  bb[1] = T[2] * bb[2];
  bb[0] = T[1] * bb[1];
  carry = T[0] * bb[0];

#pragma unroll
  for (int c = 0; c < 4; ++c) {
    const float QF = W[c] * bb[c];
    ushort4 pk;
    pk.x = f2bf(p[c][0] * (e0[c] * QF));
    pk.y = f2bf(p[c][1] * (e1[c] * QF));
    pk.z = f2bf(p[c][2] * (e2[c] * QF));
    pk.w = f2bf(p[c][3] * QF);
    *(ushort4*)&pw[lq * PSTR + c * 16 + quad * 4] = pk;  // [query][key] row-major
  }
  __asm__ volatile("s_waitcnt lgkmcnt(0)" ::: "memory");  // P visible to own wave
  const short8 pA = *(const short8*)&pw[lq * PSTR + quad * 8];       // keys j0+0..31
  const short8 pB = *(const short8*)&pw[lq * PSTR + 32 + quad * 8];  // keys j0+32..63
#pragma unroll
  for (int tt = 0; tt < 4; ++tt) {
    o[tt] = __builtin_amdgcn_mfma_f32_16x16x32_bf16(vfA[tt], pA, o[tt], 0, 0, 0);
    o[tt] = __builtin_amdgcn_mfma_f32_16x16x32_bf16(vfB[tt], pB, o[tt], 0, 0, 0);
  }
  // DS is in-order per wave: next tile's ds_write cannot pass the reads above.
}

__global__ __launch_bounds__(256, 4) void sba_attn(
    const u16* __restrict__ Q, const u16* __restrict__ Km,
    const u16* __restrict__ Vt, u16* __restrict__ AO) {
  __shared__ __align__(16) u16 lK[2][64 * 64];          // 16 KiB (dbuf K tile)
  __shared__ __align__(16) u16 lV[2][64 * 64];          // 16 KiB (dbuf V tile)
  __shared__ __align__(16) u16 lP[4][16 * PSTR];        //  9216 B (per-wave P)
  const int tid = threadIdx.x;
  const int lane = tid & 63;
  const int wave = tid >> 6;
  const int lq = lane & 15, quad = lane >> 4;
  const int blk = blockIdx.x;                 // 1024 blocks
  const int bh = blk & 63;                    // head on fixed XCD (blk%8)
  const int b  = 15 - (blk >> 6);             // LPT: 16-tile blocks first
  const int q0w = (b << 6) + (wave << 4);     // this wave's 16 queries
  const int NT = b + 1;                       // shared 64-key tiles

  // Q B-frags (pre-scaled by 1/8 in gemm_qkv): B[n=query=lq][k=d]
  const u16* qb = Q + ((size_t)bh * 1024 + q0w) * 64;
  const short8 qf0 = *(const short8*)&qb[lq * 64 + quad * 8];
  const short8 qf1 = *(const short8*)&qb[lq * 64 + 32 + quad * 8];

  const u16* kb0 = Km + (size_t)bh * 65536;
  const u16* vb  = Vt + (size_t)bh * 65536;

  floatx4 o[4];
#pragma unroll
  for (int tt = 0; tt < 4; ++tt) o[tt] = (floatx4)0.f;
  float carry = 1.f;
  u16* pw = &lP[wave][0];

  // --- block-shared double-buffered sweep, diagonal tile first ---
  int j0 = b << 6;
  stage_kv(tid, kb0, vb, j0, lK[0], lV[0]);
  __asm__ volatile("s_waitcnt vmcnt(0)" ::: "memory");
  __syncthreads();
  if (NT > 1) stage_kv(tid, kb0, vb, j0 - 64, lK[1], lV[1]);
  sba_tile_lds<true>(j0, q0w, lq, quad, lK[0], lV[0], pw, qf0, qf1, o, carry);
  int cur = 1;
  for (int i = 1; i < NT; ++i) {
    j0 -= 64;
    __asm__ volatile("s_waitcnt vmcnt(0)" ::: "memory");  // own stage landed
    __syncthreads();                                      // all stages + reads done
    if (i + 1 < NT) stage_kv(tid, kb0, vb, j0 - 64, lK[cur ^ 1], lV[cur ^ 1]);
    sba_tile_lds<false>(j0, q0w, lq, quad, lK[cur], lV[cur], pw, qf0, qf1, o, carry);
    cur ^= 1;
  }

  // O^T (d=tt*16+quad*4+r, query=lq) -> LDS [query][d] -> coalesced 16B stores
#pragma unroll
  for (int tt = 0; tt < 4; ++tt) {
    ushort4 pk;
    pk.x = f2bf(o[tt][0]); pk.y = f2bf(o[tt][1]);
    pk.z = f2bf(o[tt][2]); pk.w = f2bf(o[tt][3]);
    *(ushort4*)&pw[lq * PSTR + tt * 16 + quad * 4] = pk;
  }
  __asm__ volatile("s_waitcnt lgkmcnt(0)" ::: "memory");
  const int bo = bh >> 5, hd = bh & 31;
#pragma unroll
  for (int ps = 0; ps < 2; ++ps) {
    const int row = lane >> 2;
    const int colu = ((lane & 3) + 4 * ps) * 8;
    const short8 val = *(const short8*)&pw[row * PSTR + colu];
    *(short8*)&AO[((size_t)bo * 1024 + q0w + row) * 2048 + hd * 64 + colu] = val;
  }
}

extern "C" void kernel_launch(void* const* d_in, const int* in_sizes, int n_in,
                              void* d_out, int out_size, void* d_ws, size_t ws_size,
                              hipStream_t stream) {
  const float* H  = (const float*)d_in[0];
  const float* Wq = (const float*)d_in[1];
  const float* Wk = (const float*)d_in[2];
  const float* Wv = (const float*)d_in[3];
  const float* Wo = (const float*)d_in[4];

  u16* ws = (u16*)d_ws;
  u16* Hb  = ws;                  // [2048,2048] 8MB  (reused as ao after gemm_qkv)
  u16* Wqb = ws + 1 * 4194304;
  u16* Wkb = ws + 2 * 4194304;
  u16* Wvb = ws + 3 * 4194304;
  u16* Wob = ws + 4 * 4194304;
  u16* q   = ws + 5 * 4194304;    // [64,1024,64], pre-scaled by 1/8
  u16* k   = ws + 6 * 4194304;
  u16* vt  = ws + 7 * 4194304;    // [64,64,1024]
  u16* ao  = Hb;                  // alias: H consumed by gemm_qkv before sba_attn writes
  // split-K partials (fp32, 16MB each) over DEAD slots:
  //   P0 over Wqb+Wkb (dead after gemm_qkv); P1 over q+k (dead after sba_attn)
  float* P0 = (float*)(ws + 1 * 4194304);
  float* P1 = (float*)(ws + 5 * 4194304);

  dim3 gc(4096, 5);
  cvt_all<<<gc, 256, 0, stream>>>(H, Wq, Wk, Wv, Wo, ws);

  dim3 gq(16, 48);
  gemm_qkv<<<gq, 256, 0, stream>>>(Hb, Wqb, Wkb, Wvb, q, k, vt);
  sba_attn<<<1024, 256, 0, stream>>>(q, k, vt, ao);
  dim3 go(16, 16, 2);
  gemm_out<<<go, 256, 0, stream>>>(ao, Wob, P0, P1);
  reduce_add<<<4096, 256, 0, stream>>>(P0, P1, (float*)d_out);
}

// Round 9
// 243.041 us; speedup vs baseline: 1.3781x; 1.0076x over previous
//
#include <hip/hip_runtime.h>
#include <math.h>

typedef unsigned short u16;
typedef __attribute__((ext_vector_type(8))) short short8;   // 8 bf16 = 4 VGPRs
typedef __attribute__((ext_vector_type(4))) float floatx4;  // MFMA 16x16 C/D

// fp32 -> bf16 round-to-nearest-even
__device__ __forceinline__ u16 f2bf(float f) {
  union { float f; unsigned u; } v; v.f = f;
  unsigned r = (v.u + 0x7FFFu + ((v.u >> 16) & 1u)) >> 16;
  return (u16)r;
}

// async global->LDS, 16B per lane; LDS dest must be wave-uniform base + lane*16
#define GLD16(gp, lp) __builtin_amdgcn_global_load_lds(                      \
    (__attribute__((address_space(1))) void*)(gp),                           \
    (__attribute__((address_space(3))) void*)(lp), 16, 0, 0)

// ---------------------------------------------------------------------------
// f32 -> bf16 conversion: 5 tensors of 4194304 elements each, contiguous dst.
// ---------------------------------------------------------------------------
__global__ __launch_bounds__(256) void cvt_all(
    const float* __restrict__ H, const float* __restrict__ Wq,
    const float* __restrict__ Wk, const float* __restrict__ Wv,
    const float* __restrict__ Wo, u16* __restrict__ dst) {
  const float* srcs[5] = {H, Wq, Wk, Wv, Wo};
  const int sel = blockIdx.y;
  const float* s = srcs[sel];
  u16* d = dst + (size_t)sel * 4194304;
  const int idx = (blockIdx.x * 256 + threadIdx.x) * 4;
  const float4 v = *(const float4*)(s + idx);
  ushort4 o;
  o.x = f2bf(v.x); o.y = f2bf(v.y); o.z = f2bf(v.z); o.w = f2bf(v.w);
  *(ushort4*)(d + idx) = o;
}

// ---------------------------------------------------------------------------
// GEMM core: C[m,n] = sum_k A[m,k] * B[n,k]  (B^T layout)
// 128x128 tile, BK=64, 4 waves each computing 64x64 (4x4 MFMA tiles).
// LDS column-chunk XOR swizzle vs 16-way bank conflicts (see R5 notes).
// mode 1: head-split bf16   [bh,1024,64]   (Q,K; cscale folds 1/sqrt(D) into Q)
// mode 2: head-split-T bf16 [bh,64,1024]   (V^T)
// ---------------------------------------------------------------------------
__device__ __forceinline__ void gemm_core(const u16* __restrict__ A,
                                          const u16* __restrict__ B,
                                          u16* __restrict__ Cb,
                                          int M0, int N0, int mode, float cscale,
                                          u16* lA, u16* lB) {
  const int tid = threadIdx.x;
  const int lane = tid & 63;
  const int wave = tid >> 6;
  const int lq = lane & 15, quad = lane >> 4;
  const int wm = wave & 1, wn = wave >> 1;

  floatx4 acc[4][4];
#pragma unroll
  for (int i = 0; i < 4; ++i)
#pragma unroll
    for (int j = 0; j < 4; ++j) acc[i][j] = (floatx4)0.f;

  const int srow = tid >> 3;        // 0..31
  const int cc = tid & 7;           // column chunk 0..7

  for (int k0 = 0; k0 < 2048; k0 += 64) {
    __syncthreads();
#pragma unroll
    for (int r = 0; r < 4; ++r) {
      const int row = r * 32 + srow;
      const int gcol = ((cc ^ (row & 7)) << 3);   // swizzled global chunk
      const int flat = row * 64 + (cc << 3);      // contiguous LDS dest
      GLD16(A + (size_t)(M0 + row) * 2048 + k0 + gcol, lA + flat);
      GLD16(B + (size_t)(N0 + row) * 2048 + k0 + gcol, lB + flat);
    }
    __syncthreads();
    const int sw = lq & 7;
#pragma unroll
    for (int ks8 = 0; ks8 < 8; ks8 += 4) {        // ks = ks8*8 in {0,32}
      short8 af[4], bf[4];
#pragma unroll
      for (int t = 0; t < 4; ++t)
        af[t] = *(const short8*)&lA[(wm * 64 + t * 16 + lq) * 64 + (((quad + ks8) ^ sw) << 3)];
#pragma unroll
      for (int t = 0; t < 4; ++t)
        bf[t] = *(const short8*)&lB[(wn * 64 + t * 16 + lq) * 64 + (((quad + ks8) ^ sw) << 3)];
#pragma unroll
      for (int i = 0; i < 4; ++i)
#pragma unroll
        for (int j = 0; j < 4; ++j)
          acc[i][j] = __builtin_amdgcn_mfma_f32_16x16x32_bf16(af[i], bf[j], acc[i][j], 0, 0, 0);
    }
  }

  // epilogue: C/D layout col=lane&15, row=quad*4+reg
#pragma unroll
  for (int i = 0; i < 4; ++i)
#pragma unroll
    for (int j = 0; j < 4; ++j)
#pragma unroll
      for (int r = 0; r < 4; ++r) {
        const int m = M0 + wm * 64 + i * 16 + quad * 4 + r;
        const int n = N0 + wn * 64 + j * 16 + lq;
        const int bh = ((m >> 10) << 5) | (n >> 6);  // b*32 + head
        size_t addr;
        if (mode == 1) addr = ((size_t)bh * 1024 + (m & 1023)) * 64 + (n & 63);
        else           addr = ((size_t)bh * 64 + (n & 63)) * 1024 + (m & 1023);
        Cb[addr] = f2bf(acc[i][j][r] * cscale);
      }
}

__global__ __launch_bounds__(256, 3) void gemm_qkv(
    const u16* __restrict__ H,
    const u16* __restrict__ Wq, const u16* __restrict__ Wk, const u16* __restrict__ Wv,
    u16* __restrict__ q, u16* __restrict__ k, u16* __restrict__ vt) {
  __shared__ __align__(16) u16 lA[128 * 64];
  __shared__ __align__(16) u16 lB[128 * 64];
  const int M0 = blockIdx.x * 128;
  const int sel = blockIdx.y >> 4;        // 0:Q 1:K 2:V
  const int N0 = (blockIdx.y & 15) * 128;
  const u16* B = (sel == 0) ? Wq : (sel == 1) ? Wk : Wv;
  u16* C = (sel == 0) ? q : (sel == 1) ? k : vt;
  gemm_core(H, B, C, M0, N0, (sel == 2) ? 2 : 1,
            (sel == 0) ? 0.125f : 1.f, lA, lB);
}

// ---------------------------------------------------------------------------
// R14 gemm_out2: the old 128x128 gemm_out ran at 256 blocks = 1/CU (~118us,
// ~146 TF); split-K=2 was ~neutral (2/CU + 80MB partial traffic). Fix the
// parallelism properly: BM=128 x BN=64 tile -> grid (16,32) = 512 blocks,
// FULL K (32 iters, same long-K efficiency as gemm_qkv), no partials, no
// reduce pass. acc[4][2]=32 AGPR + ~24 frag VGPR fits (256,4)'s 128-cap
// with headroom -> 2 blocks/CU resident (8 waves/CU, 2x today).
// Staging/swizzle/barrier skeleton copied from verified gemm_core.
// ---------------------------------------------------------------------------
__global__ __launch_bounds__(256, 4) void gemm_out2(
    const u16* __restrict__ A, const u16* __restrict__ W,
    float* __restrict__ C) {
  __shared__ __align__(16) u16 lA[128 * 64];   // 16 KiB
  __shared__ __align__(16) u16 lB[64 * 64];    //  8 KiB
  const int tid = threadIdx.x;
  const int lane = tid & 63;
  const int wave = tid >> 6;
  const int lq = lane & 15, quad = lane >> 4;
  const int wm = wave & 1, wn = wave >> 1;     // wn in 0..1 (N-half of 64)
  const int M0 = blockIdx.x * 128, N0 = blockIdx.y * 64;

  floatx4 acc[4][2];
#pragma unroll
  for (int i = 0; i < 4; ++i)
#pragma unroll
    for (int j = 0; j < 2; ++j) acc[i][j] = (floatx4)0.f;

  const int srow = tid >> 3;        // 0..31
  const int cc = tid & 7;           // column chunk 0..7

  for (int k0 = 0; k0 < 2048; k0 += 64) {
    __syncthreads();
#pragma unroll
    for (int r = 0; r < 4; ++r) {                 // A: 128 rows
      const int row = r * 32 + srow;
      const int gcol = ((cc ^ (row & 7)) << 3);
      GLD16(A + (size_t)(M0 + row) * 2048 + k0 + gcol, lA + row * 64 + (cc << 3));
    }
#pragma unroll
    for (int it = 0; it < 2; ++it) {              // B: 64 rows
      const int row = it * 32 + srow;
      const int gcol = ((cc ^ (row & 7)) << 3);
      GLD16(W + (size_t)(N0 + row) * 2048 + k0 + gcol, lB + row * 64 + (cc << 3));
    }
    __syncthreads();
    const int sw = lq & 7;
#pragma unroll
    for (int ks8 = 0; ks8 < 8; ks8 += 4) {        // ks = ks8*8 in {0,32}
      short8 af[4], bf[2];
#pragma unroll
      for (int t = 0; t < 4; ++t)
        af[t] = *(const short8*)&lA[(wm * 64 + t * 16 + lq) * 64 + (((quad + ks8) ^ sw) << 3)];
#pragma unroll
      for (int t = 0; t < 2; ++t)
        bf[t] = *(const short8*)&lB[(wn * 32 + t * 16 + lq) * 64 + (((quad + ks8) ^ sw) << 3)];
#pragma unroll
      for (int i = 0; i < 4; ++i)
#pragma unroll
        for (int j = 0; j < 2; ++j)
          acc[i][j] = __builtin_amdgcn_mfma_f32_16x16x32_bf16(af[i], bf[j], acc[i][j], 0, 0, 0);
    }
  }

  // epilogue: C/D layout col=lane&15, row=quad*4+reg; fp32 row-major out
#pragma unroll
  for (int i = 0; i < 4; ++i)
#pragma unroll
    for (int j = 0; j < 2; ++j)
#pragma unroll
      for (int r = 0; r < 4; ++r) {
        const int m = M0 + wm * 64 + i * 16 + quad * 4 + r;
        const int n = N0 + wn * 32 + j * 16 + lq;
        C[(size_t)m * 2048 + n] = acc[i][j][r];
      }
}

// ---------------------------------------------------------------------------
// Stick-breaking attention, multiplicative form, transposed z:
//   p = sigmoid(z), att[i,j] = p(i,j) * prod_{j<k<i} (1 - p(i,k))
// z' = K·Q^T via MFMA -> C-layout: lane holds query=lq, keys=16c+quad*4+r.
// P written [query][key] (B-frag layout), PV = MFMA(A=Vt, B=P') -> O^T,
// transposed back through LDS for coalesced stores.
//
// R12 (WIN, 278->245us): BLOCK-COOPERATIVE staging. One block = 64
// consecutive queries (4 waves x 16); all waves sweep the SAME j0 from the
// diagonal tile down to 0, so K/V 64x64 tiles are block-shared: staged once
// per tile via GLD16 (coalesced 16B), double-buffered, async under compute.
// Replaced the R5-R11 invariant (16 scattered VMEM instrs/wave/tile) that
// kept sba_attn pinned at ~70us across occupancy/ILP/scan variants.
// sba_attn now ~37us (back-solved; below top-5 cutoff).
// Sigmoid/butterfly-scan/carry/P->PV: verbatim R11 (correctness-proven).
// ---------------------------------------------------------------------------
#define PSTR 72   // P slab row stride in u16 (64 + 8 pad; rows 144B, 16B-aligned)

__device__ __forceinline__ void stage_kv(
    int tid, const u16* __restrict__ kb0, const u16* __restrict__ vb, int j0,
    u16* dK, u16* dV) {
#pragma unroll
  for (int it = 0; it < 2; ++it) {
    const int s = it * 256 + tid;           // slot 0..511
    const int row = s >> 3, cc = s & 7;     // 64 rows x 8 chunks of 16B
    const int gc = (cc ^ (row & 7)) << 3;   // pre-swizzled global chunk
    const int flat = row * 64 + (cc << 3);  // contiguous LDS dest (GLD16 law)
    GLD16(kb0 + (size_t)(j0 + row) * 64 + gc, dK + flat);
    GLD16(vb + (size_t)row * 1024 + j0 + gc, dV + flat);
  }
}

template <bool MASKED>
__device__ __forceinline__ void sba_tile_lds(
    int j0, int q0w, int lq, int quad,
    const u16* __restrict__ lK, const u16* __restrict__ lV, u16* pw,
    const short8& qf0, const short8& qf1,
    floatx4 (&o)[4], float& carry) {
  const int sw = lq & 7;
  // K A-frags from LDS (swizzled chunks): A[m=key 16c+lq][k=d chunk]
  short8 kf0[4], kf1[4];
#pragma unroll
  for (int c = 0; c < 4; ++c) {
    const u16* kr = &lK[(16 * c + lq) * 64];
    kf0[c] = *(const short8*)&kr[(quad ^ sw) << 3];
    kf1[c] = *(const short8*)&kr[((quad + 4) ^ sw) << 3];
  }
  floatx4 zc[4];
#pragma unroll
  for (int c = 0; c < 4; ++c) {
    floatx4 z = (floatx4)0.f;
    z = __builtin_amdgcn_mfma_f32_16x16x32_bf16(kf0[c], qf0, z, 0, 0, 0);
    z = __builtin_amdgcn_mfma_f32_16x16x32_bf16(kf1[c], qf1, z, 0, 0, 0);
    zc[c] = z;
  }
  // V A-frags from LDS: rows = d (tt*16+lq), key chunks quad / quad+4
  short8 vfA[4], vfB[4];
#pragma unroll
  for (int tt = 0; tt < 4; ++tt) {
    const u16* vr = &lV[(tt * 16 + lq) * 64];
    vfA[tt] = *(const short8*)&vr[(quad ^ sw) << 3];
    vfB[tt] = *(const short8*)&vr[((quad + 4) ^ sw) << 3];
  }

  // sigmoid + within-quad exclusive suffixes: all 16 (c,r) pairs independent
  float p[4][4], e0[4], e1[4], e2[4], x[4];
#pragma unroll
  for (int c = 0; c < 4; ++c) {
    float g[4];
#pragma unroll
    for (int r = 0; r < 4; ++r) {
      const float z = zc[c][r];
      const float e = __expf(-z);
      float pp = __builtin_amdgcn_rcpf(1.f + e);   // sigmoid
      float gg = e * pp;                            // 1 - sigmoid
      if (MASKED) {
        const bool valid = (j0 + 16 * c + quad * 4 + r) < (q0w + lq);
        gg = valid ? gg : 1.f;
        pp = valid ? pp : 0.f;
      }
      p[c][r] = pp; g[r] = gg;
    }
    e2[c] = g[3];
    e1[c] = e2[c] * g[2];
    e0[c] = e1[c] * g[1];
    x[c]  = e0[c] * g[0];      // product of this quad-chunk's 4 keys
  }

  // 2-level butterfly scan, all chunks in parallel (chain: 2 shuffle levels)
  float s1[4], pp[4], s2[4];
#pragma unroll
  for (int c = 0; c < 4; ++c) s1[c] = __shfl_xor(x[c], 16);
#pragma unroll
  for (int c = 0; c < 4; ++c) pp[c] = x[c] * s1[c];      // pair {q, q^1} product
#pragma unroll
  for (int c = 0; c < 4; ++c) s2[c] = __shfl_xor(pp[c], 32);  // other pair's product
  float T[4], W[4];
#pragma unroll
  for (int c = 0; c < 4; ++c) {
    T[c] = pp[c] * s2[c];                       // chunk total (quad-uniform)
    const float hi = (quad & 1) ? 1.f : s1[c];  // within-pair suffix (x of q+1)
    W[c] = hi * ((quad < 2) ? s2[c] : 1.f);     // prod over quads > mine
  }
  // bb[c] = carry * prod_{c'>c} T[c'] (higher c = closer to diagonal)
  float bb[4];
  bb[3] = carry;
  bb[2] = T[3] * bb[3];
  bb[1] = T[2] * bb[2];
  bb[0] = T[1] * bb[1];
  carry = T[0] * bb[0];

#pragma unroll
  for (int c = 0; c < 4; ++c) {
    const float QF = W[c] * bb[c];
    ushort4 pk;
    pk.x = f2bf(p[c][0] * (e0[c] * QF));
    pk.y = f2bf(p[c][1] * (e1[c] * QF));
    pk.z = f2bf(p[c][2] * (e2[c] * QF));
    pk.w = f2bf(p[c][3] * QF);
    *(ushort4*)&pw[lq * PSTR + c * 16 + quad * 4] = pk;  // [query][key] row-major
  }
  __asm__ volatile("s_waitcnt lgkmcnt(0)" ::: "memory");  // P visible to own wave
  const short8 pA = *(const short8*)&pw[lq * PSTR + quad * 8];       // keys j0+0..31
  const short8 pB = *(const short8*)&pw[lq * PSTR + 32 + quad * 8];  // keys j0+32..63
#pragma unroll
  for (int tt = 0; tt < 4; ++tt) {
    o[tt] = __builtin_amdgcn_mfma_f32_16x16x32_bf16(vfA[tt], pA, o[tt], 0, 0, 0);
    o[tt] = __builtin_amdgcn_mfma_f32_16x16x32_bf16(vfB[tt], pB, o[tt], 0, 0, 0);
  }
  // DS is in-order per wave: next tile's ds_write cannot pass the reads above.
}

__global__ __launch_bounds__(256, 4) void sba_attn(
    const u16* __restrict__ Q, const u16* __restrict__ Km,
    const u16* __restrict__ Vt, u16* __restrict__ AO) {
  __shared__ __align__(16) u16 lK[2][64 * 64];          // 16 KiB (dbuf K tile)
  __shared__ __align__(16) u16 lV[2][64 * 64];          // 16 KiB (dbuf V tile)
  __shared__ __align__(16) u16 lP[4][16 * PSTR];        //  9216 B (per-wave P)
  const int tid = threadIdx.x;
  const int lane = tid & 63;
  const int wave = tid >> 6;
  const int lq = lane & 15, quad = lane >> 4;
  const int blk = blockIdx.x;                 // 1024 blocks
  const int bh = blk & 63;                    // head on fixed XCD (blk%8)
  const int b  = 15 - (blk >> 6);             // LPT: 16-tile blocks first
  const int q0w = (b << 6) + (wave << 4);     // this wave's 16 queries
  const int NT = b + 1;                       // shared 64-key tiles

  // Q B-frags (pre-scaled by 1/8 in gemm_qkv): B[n=query=lq][k=d]
  const u16* qb = Q + ((size_t)bh * 1024 + q0w) * 64;
  const short8 qf0 = *(const short8*)&qb[lq * 64 + quad * 8];
  const short8 qf1 = *(const short8*)&qb[lq * 64 + 32 + quad * 8];

  const u16* kb0 = Km + (size_t)bh * 65536;
  const u16* vb  = Vt + (size_t)bh * 65536;

  floatx4 o[4];
#pragma unroll
  for (int tt = 0; tt < 4; ++tt) o[tt] = (floatx4)0.f;
  float carry = 1.f;
  u16* pw = &lP[wave][0];

  // --- block-shared double-buffered sweep, diagonal tile first ---
  int j0 = b << 6;
  stage_kv(tid, kb0, vb, j0, lK[0], lV[0]);
  __asm__ volatile("s_waitcnt vmcnt(0)" ::: "memory");
  __syncthreads();
  if (NT > 1) stage_kv(tid, kb0, vb, j0 - 64, lK[1], lV[1]);
  sba_tile_lds<true>(j0, q0w, lq, quad, lK[0], lV[0], pw, qf0, qf1, o, carry);
  int cur = 1;
  for (int i = 1; i < NT; ++i) {
    j0 -= 64;
    __asm__ volatile("s_waitcnt vmcnt(0)" ::: "memory");  // own stage landed
    __syncthreads();                                      // all stages + reads done
    if (i + 1 < NT) stage_kv(tid, kb0, vb, j0 - 64, lK[cur ^ 1], lV[cur ^ 1]);
    sba_tile_lds<false>(j0, q0w, lq, quad, lK[cur], lV[cur], pw, qf0, qf1, o, carry);
    cur ^= 1;
  }

  // O^T (d=tt*16+quad*4+r, query=lq) -> LDS [query][d] -> coalesced 16B stores
#pragma unroll
  for (int tt = 0; tt < 4; ++tt) {
    ushort4 pk;
    pk.x = f2bf(o[tt][0]); pk.y = f2bf(o[tt][1]);
    pk.z = f2bf(o[tt][2]); pk.w = f2bf(o[tt][3]);
    *(ushort4*)&pw[lq * PSTR + tt * 16 + quad * 4] = pk;
  }
  __asm__ volatile("s_waitcnt lgkmcnt(0)" ::: "memory");
  const int bo = bh >> 5, hd = bh & 31;
#pragma unroll
  for (int ps = 0; ps < 2; ++ps) {
    const int row = lane >> 2;
    const int colu = ((lane & 3) + 4 * ps) * 8;
    const short8 val = *(const short8*)&pw[row * PSTR + colu];
    *(short8*)&AO[((size_t)bo * 1024 + q0w + row) * 2048 + hd * 64 + colu] = val;
  }
}

extern "C" void kernel_launch(void* const* d_in, const int* in_sizes, int n_in,
                              void* d_out, int out_size, void* d_ws, size_t ws_size,
                              hipStream_t stream) {
  const float* H  = (const float*)d_in[0];
  const float* Wq = (const float*)d_in[1];
  const float* Wk = (const float*)d_in[2];
  const float* Wv = (const float*)d_in[3];
  const float* Wo = (const float*)d_in[4];

  u16* ws = (u16*)d_ws;
  u16* Hb  = ws;                  // [2048,2048] 8MB  (reused as ao after gemm_qkv)
  u16* Wqb = ws + 1 * 4194304;
  u16* Wkb = ws + 2 * 4194304;
  u16* Wvb = ws + 3 * 4194304;
  u16* Wob = ws + 4 * 4194304;
  u16* q   = ws + 5 * 4194304;    // [64,1024,64], pre-scaled by 1/8
  u16* k   = ws + 6 * 4194304;
  u16* vt  = ws + 7 * 4194304;    // [64,64,1024]
  u16* ao  = Hb;                  // alias: H consumed by gemm_qkv before sba_attn writes

  dim3 gc(4096, 5);
  cvt_all<<<gc, 256, 0, stream>>>(H, Wq, Wk, Wv, Wo, ws);

  dim3 gq(16, 48);
  gemm_qkv<<<gq, 256, 0, stream>>>(Hb, Wqb, Wkb, Wvb, q, k, vt);
  sba_attn<<<1024, 256, 0, stream>>>(q, k, vt, ao);
  dim3 go(16, 32);
  gemm_out2<<<go, 256, 0, stream>>>(ao, Wob, (float*)d_out);
}